// Round 1
// baseline (298.541 us; speedup 1.0000x reference)
//
#include <hip/hip_runtime.h>

typedef __bf16 bf16;
typedef __bf16 bf16x8 __attribute__((ext_vector_type(8)));
typedef float  f32x4  __attribute__((ext_vector_type(4)));

// Problem constants
#define NSPEC   512          // 256 pairs * 2
#define PPEAKS  512
#define BOUT    9999         // GROUPS*3
#define K0A     10112        // BOUT padded to 316*32 (multiple of KSPLIT*BK=128)
#define N00     1024         // 1000 padded
#define N01     896          // 800 padded
#define N02     896
#define N03     512          // 400 padded

// ---------------- init kernels ----------------
__global__ __launch_bounds__(256) void init_x(const float* __restrict__ bb,
                                              float* __restrict__ xs) {
    int c = blockIdx.x * 256 + threadIdx.x;   // 0..10239
    int r = blockIdx.y;
    if (c < BOUT) xs[(size_t)r * BOUT + c] = bb[c];
}

__global__ __launch_bounds__(256) void init_h(const float* __restrict__ b0,
                                              const float* __restrict__ b1,
                                              const float* __restrict__ b2,
                                              const float* __restrict__ be,
                                              float* __restrict__ H0, float* __restrict__ H1,
                                              float* __restrict__ H2, float* __restrict__ E) {
    int c = blockIdx.x * 256 + threadIdx.x;   // 0..3327
    int r = blockIdx.y;
    if (c < 1024)      { H0[(size_t)r*N00 + c] = (c < 1000) ? b0[c] : 0.f; }
    else if (c < 1920) { int j = c - 1024; H1[(size_t)r*N01 + j] = (j < 800) ? b1[j] : 0.f; }
    else if (c < 2816) { int j = c - 1920; H2[(size_t)r*N02 + j] = (j < 800) ? b2[j] : 0.f; }
    else if (c < 3328) { int j = c - 2816; E [(size_t)r*N03 + j] = (j < 400) ? be[j] : 0.f; }
}

// ---------------- peak scatter ----------------
__global__ __launch_bounds__(256) void bin_scatter(const float* __restrict__ mz,
                                                   const float* __restrict__ inten,
                                                   const float* __restrict__ bw,
                                                   float* __restrict__ xs) {
    int t = blockIdx.x * 256 + threadIdx.x;   // 0..262143
    float m = mz[t];
    float v = inten[t];
    bool mask = (m >= 0.0f) && (m < 1000.0f);
    int idx = (int)(m / 0.01f);               // IEEE div + trunc, matches astype(int32)
    idx = min(max(idx, 0), 99999);
    if (mask && idx < 99990) {
        int g = idx / 30;
        int i = idx - g * 30;
        float val = sqrtf(v);                 // inten ** 0.5
        const float* w = bw + ((size_t)g * 30 + i) * 3;
        float* x = xs + (size_t)(t >> 9) * BOUT + g * 3;
        atomicAdd(x + 0, val * w[0]);
        atomicAdd(x + 1, val * w[1]);
        atomicAdd(x + 2, val * w[2]);
    }
}

// ---------------- fp32 -> bf16 (A operand, pad K) ----------------
__global__ __launch_bounds__(256) void cvt_a(const float* __restrict__ xs,
                                             bf16* __restrict__ A) {
    int c = blockIdx.x * 256 + threadIdx.x;   // 0..10239
    int r = blockIdx.y;
    if (c < K0A)
        A[(size_t)r * K0A + c] = (c < BOUT) ? (bf16)xs[(size_t)r * BOUT + c] : (bf16)0.f;
}

// ---------------- weight transpose+convert: src (K x N) fp32 -> dst (N0 x K0) bf16 ----------------
__global__ __launch_bounds__(256) void transpose_cvt(const float* __restrict__ src,
                                                     bf16* __restrict__ dst,
                                                     int K, int N, int K0, int N0) {
    __shared__ float tile[32][33];
    int n0 = blockIdx.x * 32, k0 = blockIdx.y * 32;
    int t = threadIdx.x;
    {
        int kr = t >> 3, nc = (t & 7) * 4;
        int gk = k0 + kr;
#pragma unroll
        for (int e = 0; e < 4; ++e) {
            int gn = n0 + nc + e;
            tile[kr][nc + e] = (gk < K && gn < N) ? src[(size_t)gk * N + gn] : 0.0f;
        }
    }
    __syncthreads();
    {
        int nr = t >> 3, kc = (t & 7) * 4;
        bf16 v[4];
#pragma unroll
        for (int e = 0; e < 4; ++e) v[e] = (bf16)tile[kc + e][nr];
        // 8-byte aligned store (kc multiple of 4, K0 multiple of 32)
        *(ushort4*)&dst[(size_t)(n0 + nr) * K0 + k0 + kc] = *(ushort4*)v;
    }
}

// ---------------- bf16 MFMA GEMM, Bt layout (N0 x K0), split-K atomic fp32 epilogue ----------------
template <int BM, int BN>
__global__ __launch_bounds__(256) void gemm_bt_atomic(const bf16* __restrict__ A,
                                                      const bf16* __restrict__ Bt,
                                                      float* __restrict__ C,
                                                      int K0, int N0, int kiters) {
    constexpr int BK = 32;
    constexpr int LDS_K = BK + 8;             // pad to stagger banks
    __shared__ __align__(16) bf16 As[BM][LDS_K];
    __shared__ __align__(16) bf16 Bs[BN][LDS_K];

    const int tid = threadIdx.x;
    const int mt = blockIdx.x, nt = blockIdx.y, kp = blockIdx.z;
    const int kbase0 = kp * kiters * BK;
    const int wave = tid >> 6, lane = tid & 63;
    const int wm = wave & 1, wn = wave >> 1;  // 2x2 wave grid
    const int lrow = lane & 15, quad = lane >> 4;
    constexpr int RM = BM / 32, RN = BN / 32;

    f32x4 acc[RM][RN] = {};
    const bf16* Ag = A  + (size_t)mt * BM * K0;
    const bf16* Bg = Bt + (size_t)nt * BN * K0;

    for (int kk = 0; kk < kiters; ++kk) {
        const int k = kbase0 + kk * BK;
        // stage A tile: BM x 32, 16B chunks
#pragma unroll
        for (int i = tid; i < BM * 4; i += 256) {
            int row = i >> 2, ch = i & 3;
            *(uint4*)&As[row][ch * 8] = *(const uint4*)&Ag[(size_t)row * K0 + k + ch * 8];
        }
        // stage B tile: BN x 32
#pragma unroll
        for (int i = tid; i < BN * 4; i += 256) {
            int row = i >> 2, ch = i & 3;
            *(uint4*)&Bs[row][ch * 8] = *(const uint4*)&Bg[(size_t)row * K0 + k + ch * 8];
        }
        __syncthreads();

        bf16x8 af[RM], bfr[RN];
#pragma unroll
        for (int im = 0; im < RM; ++im)
            af[im] = *(const bf16x8*)&As[wm * (BM / 2) + im * 16 + lrow][quad * 8];
#pragma unroll
        for (int in = 0; in < RN; ++in)
            bfr[in] = *(const bf16x8*)&Bs[wn * (BN / 2) + in * 16 + lrow][quad * 8];
#pragma unroll
        for (int im = 0; im < RM; ++im)
#pragma unroll
            for (int in = 0; in < RN; ++in)
                acc[im][in] = __builtin_amdgcn_mfma_f32_16x16x32_bf16(af[im], bfr[in], acc[im][in], 0, 0, 0);
        __syncthreads();
    }

    // epilogue: C/D layout col=lane&15, row=quad*4+reg
#pragma unroll
    for (int im = 0; im < RM; ++im) {
        int row0 = mt * BM + wm * (BM / 2) + im * 16 + quad * 4;
#pragma unroll
        for (int in = 0; in < RN; ++in) {
            int col = nt * BN + wn * (BN / 2) + in * 16 + lrow;
#pragma unroll
            for (int r = 0; r < 4; ++r)
                atomicAdd(&C[(size_t)(row0 + r) * N0 + col], acc[im][in][r]);
        }
    }
}

// ---------------- relu + cvt to bf16 ----------------
__global__ __launch_bounds__(256) void relu_cvt(const float* __restrict__ H,
                                                bf16* __restrict__ Hb, int total) {
    int t = blockIdx.x * 256 + threadIdx.x;
    if (t < total) {
        float v = H[t];
        Hb[t] = (bf16)(v > 0.f ? v : 0.f);
    }
}

// ---------------- cosine similarity over pairs ----------------
__global__ __launch_bounds__(64) void cosine_k(const float* __restrict__ E,
                                               float* __restrict__ out) {
    int b = blockIdx.x;
    int lane = threadIdx.x;
    const float* e1 = E + (size_t)(2 * b) * N03;
    const float* e2 = e1 + N03;
    float dot = 0.f, s1 = 0.f, s2 = 0.f;
#pragma unroll
    for (int i = lane; i < N03; i += 64) {    // pad cols are exactly 0
        float a = e1[i], c = e2[i];
        dot += a * c; s1 += a * a; s2 += c * c;
    }
#pragma unroll
    for (int off = 32; off; off >>= 1) {
        dot += __shfl_down(dot, off);
        s1  += __shfl_down(s1, off);
        s2  += __shfl_down(s2, off);
    }
    if (lane == 0) {
        float n1 = fmaxf(sqrtf(s1), 1e-6f);
        float n2 = fmaxf(sqrtf(s2), 1e-6f);
        out[b] = dot / (n1 * n2);
    }
}

extern "C" void kernel_launch(void* const* d_in, const int* in_sizes, int n_in,
                              void* d_out, int out_size, void* d_ws, size_t ws_size,
                              hipStream_t stream) {
    const float* mz    = (const float*)d_in[0];
    const float* inten = (const float*)d_in[1];
    const float* bw    = (const float*)d_in[2];
    const float* bb    = (const float*)d_in[3];
    const float* w0    = (const float*)d_in[4];
    const float* b0    = (const float*)d_in[5];
    const float* w1    = (const float*)d_in[6];
    const float* b1    = (const float*)d_in[7];
    const float* w2    = (const float*)d_in[8];
    const float* b2    = (const float*)d_in[9];
    const float* we    = (const float*)d_in[10];
    const float* be    = (const float*)d_in[11];
    float* out = (float*)d_out;

    char* ws = (char*)d_ws;
    size_t off = 0;
    auto alloc = [&](size_t bytes) { char* p = ws + off; off += (bytes + 255) & ~(size_t)255; return p; };
    float* xs  = (float*)alloc((size_t)NSPEC * BOUT * 4);
    bf16*  A   = (bf16*) alloc((size_t)NSPEC * K0A * 2);
    bf16*  B0t = (bf16*) alloc((size_t)N00 * K0A * 2);
    bf16*  B1t = (bf16*) alloc((size_t)N01 * 1024 * 2);
    bf16*  B2t = (bf16*) alloc((size_t)N02 * 896 * 2);
    bf16*  BEt = (bf16*) alloc((size_t)N03 * 896 * 2);
    float* H0  = (float*)alloc((size_t)NSPEC * N00 * 4);
    bf16*  H0b = (bf16*) alloc((size_t)NSPEC * N00 * 2);
    float* H1  = (float*)alloc((size_t)NSPEC * N01 * 4);
    bf16*  H1b = (bf16*) alloc((size_t)NSPEC * N01 * 2);
    float* H2  = (float*)alloc((size_t)NSPEC * N02 * 4);
    bf16*  H2b = (bf16*) alloc((size_t)NSPEC * N02 * 2);
    float* E   = (float*)alloc((size_t)NSPEC * N03 * 4);

    // init (fold biases into accumulators; xs gets binner_b broadcast)
    init_x<<<dim3(40, 512), 256, 0, stream>>>(bb, xs);
    init_h<<<dim3(13, 512), 256, 0, stream>>>(b0, b1, b2, be, H0, H1, H2, E);
    // sparse binning + binner matmul fused as scatter
    bin_scatter<<<1024, 256, 0, stream>>>(mz, inten, bw, xs);
    cvt_a<<<dim3(40, 512), 256, 0, stream>>>(xs, A);
    // weights -> bf16 N-major (k contiguous)
    transpose_cvt<<<dim3(32, 316), 256, 0, stream>>>(w0, B0t, BOUT, 1000, K0A, N00);
    transpose_cvt<<<dim3(28, 32),  256, 0, stream>>>(w1, B1t, 1000, 800, 1024, N01);
    transpose_cvt<<<dim3(28, 28),  256, 0, stream>>>(w2, B2t, 800, 800, 896, N02);
    transpose_cvt<<<dim3(16, 28),  256, 0, stream>>>(we, BEt, 800, 400, 896, N03);
    // MLP
    gemm_bt_atomic<64, 128><<<dim3(8, 8, 4), 256, 0, stream>>>(A,   B0t, H0, K0A,  N00, 79);
    relu_cvt<<<2048, 256, 0, stream>>>(H0, H0b, NSPEC * N00);
    gemm_bt_atomic<64, 128><<<dim3(8, 7, 4), 256, 0, stream>>>(H0b, B1t, H1, 1024, N01, 8);
    relu_cvt<<<1792, 256, 0, stream>>>(H1, H1b, NSPEC * N01);
    gemm_bt_atomic<64, 128><<<dim3(8, 7, 4), 256, 0, stream>>>(H1b, B2t, H2, 896,  N02, 7);
    relu_cvt<<<1792, 256, 0, stream>>>(H2, H2b, NSPEC * N02);
    gemm_bt_atomic<64, 128><<<dim3(8, 4, 4), 256, 0, stream>>>(H2b, BEt, E,  896,  N03, 7);
    // cosine
    cosine_k<<<256, 64, 0, stream>>>(E, out);
}

// Round 2
// 247.789 us; speedup vs baseline: 1.2048x; 1.2048x over previous
//
#include <hip/hip_runtime.h>

typedef __bf16 bf16;
typedef __bf16 bf16x8 __attribute__((ext_vector_type(8)));
typedef float  f32x4  __attribute__((ext_vector_type(4)));

// Problem constants
#define NSPEC   512          // 256 pairs * 2
#define BOUT    9999         // GROUPS*3
#define K0A     10240        // BOUT padded to 8*20*64 (ksplit*kiters*BK)
#define N00     1024         // 1000 padded
#define N01     896          // 800 padded
#define N02     896
#define N03     448          // 400 padded to 7*64

// async global->LDS, 16B per lane; lds base must be wave-uniform (lane*16 added by HW)
__device__ __forceinline__ void gload_lds16(const bf16* g, bf16* l) {
    auto* gp = reinterpret_cast<const __attribute__((address_space(1))) unsigned int*>(
        reinterpret_cast<uintptr_t>(g));
    auto* lp = reinterpret_cast<__attribute__((address_space(3))) unsigned int*>(
        reinterpret_cast<uintptr_t>(l));
    __builtin_amdgcn_global_load_lds(gp, lp, 16, 0, 0);
}

// ---------------- fused init: xs <- broadcast binner_b (padded), H0 <- broadcast b0 ----------------
__global__ __launch_bounds__(256) void init_fused(const float* __restrict__ bb,
                                                  const float* __restrict__ b0,
                                                  float* __restrict__ xs,
                                                  float* __restrict__ H0) {
    const int XS4 = NSPEC * (K0A / 4);   // 1310720
    const int H04 = NSPEC * (N00 / 4);   // 131072
    int t = blockIdx.x * 256 + threadIdx.x;
    if (t < XS4) {
        int row = t / (K0A / 4), c = (t % (K0A / 4)) * 4;
        float4 v;
        v.x = (c + 0 < BOUT) ? bb[c + 0] : 0.f;
        v.y = (c + 1 < BOUT) ? bb[c + 1] : 0.f;
        v.z = (c + 2 < BOUT) ? bb[c + 2] : 0.f;
        v.w = (c + 3 < BOUT) ? bb[c + 3] : 0.f;
        *(float4*)&xs[(size_t)row * K0A + c] = v;
    } else if (t < XS4 + H04) {
        int u = t - XS4;
        int row = u / (N00 / 4), c = (u % (N00 / 4)) * 4;
        float4 v;
        v.x = (c + 0 < 1000) ? b0[c + 0] : 0.f;
        v.y = (c + 1 < 1000) ? b0[c + 1] : 0.f;
        v.z = (c + 2 < 1000) ? b0[c + 2] : 0.f;
        v.w = (c + 3 < 1000) ? b0[c + 3] : 0.f;
        *(float4*)&H0[(size_t)row * N00 + c] = v;
    }
}

// ---------------- peak scatter (fused binning + grouped binner matmul) ----------------
__global__ __launch_bounds__(256) void bin_scatter(const float* __restrict__ mz,
                                                   const float* __restrict__ inten,
                                                   const float* __restrict__ bw,
                                                   float* __restrict__ xs) {
    int t = blockIdx.x * 256 + threadIdx.x;   // 0..262143
    float m = mz[t];
    float v = inten[t];
    bool mask = (m >= 0.0f) && (m < 1000.0f);
    int idx = (int)(m / 0.01f);               // IEEE div + trunc, matches astype(int32)
    idx = min(max(idx, 0), 99999);
    if (mask && idx < 99990) {
        int g = idx / 30;
        float val = sqrtf(v);                 // inten ** 0.5
        const float* w = bw + (size_t)idx * 3;
        float* x = xs + (size_t)(t >> 9) * K0A + g * 3;
        atomicAdd(x + 0, val * w[0]);
        atomicAdd(x + 1, val * w[1]);
        atomicAdd(x + 2, val * w[2]);
    }
}

// ---------------- fp32 -> bf16 flat vector copy (xs is padded, contiguous) ----------------
__global__ __launch_bounds__(256) void cvt_a(const float* __restrict__ xs,
                                             bf16* __restrict__ A) {
    size_t t = (size_t)(blockIdx.x * 256 + threadIdx.x) * 4;
    float4 v = *(const float4*)&xs[t];
    bf16 o[4] = {(bf16)v.x, (bf16)v.y, (bf16)v.z, (bf16)v.w};
    *(ushort4*)&A[t] = *(ushort4*)o;
}

// ---------------- weight transpose+convert: src (K x N) fp32 -> dst (N0 x K0) bf16 ----------------
__global__ __launch_bounds__(256) void transpose_cvt(const float* __restrict__ src,
                                                     bf16* __restrict__ dst,
                                                     int K, int N, int K0, int N0) {
    __shared__ float tile[32][33];
    int n0 = blockIdx.x * 32, k0 = blockIdx.y * 32;
    int t = threadIdx.x;
    {
        int kr = t >> 3, nc = (t & 7) * 4;
        int gk = k0 + kr;
#pragma unroll
        for (int e = 0; e < 4; ++e) {
            int gn = n0 + nc + e;
            tile[kr][nc + e] = (gk < K && gn < N) ? src[(size_t)gk * N + gn] : 0.0f;
        }
    }
    __syncthreads();
    {
        int nr = t >> 3, kc = (t & 7) * 4;
        bf16 v[4];
#pragma unroll
        for (int e = 0; e < 4; ++e) v[e] = (bf16)tile[kc + e][nr];
        *(ushort4*)&dst[(size_t)(n0 + nr) * K0 + k0 + kc] = *(ushort4*)v;
    }
}

// ---------------- GEMM0: 64x64xBK64 tiles, split-K=8 XCD-pinned, async LDS staging ----------------
__global__ __launch_bounds__(256) void gemm0_splitk(const bf16* __restrict__ A,
                                                    const bf16* __restrict__ Bt,
                                                    float* __restrict__ C) {
    constexpr int K0 = K0A, KITERS = 20;
    __shared__ __align__(16) bf16 As[64 * 64];
    __shared__ __align__(16) bf16 Bs[64 * 64];
    const int bid = blockIdx.x;
    const int kp = bid & 7;                   // kp == XCD (round-robin dispatch)
    const int tile = bid >> 3;
    const int mt = tile & 7, nt = tile >> 3;
    const int tid = threadIdx.x, wave = tid >> 6, lane = tid & 63;
    const int wm = wave & 1, wn = wave >> 1;
    const int lrow = lane & 15, quad = lane >> 4;
    const int l8 = lane >> 3, lc = (lane & 7) * 8;

    const bf16* Ag = A  + (size_t)(mt * 64) * K0 + kp * KITERS * 64;
    const bf16* Bg = Bt + (size_t)(nt * 64) * K0 + kp * KITERS * 64;

    f32x4 acc[2][2] = {};
    for (int kk = 0; kk < KITERS; ++kk) {
        const int k = kk * 64;
#pragma unroll
        for (int j = 0; j < 2; ++j) {
            int row = j * 32 + wave * 8;
            gload_lds16(Ag + (size_t)(row + l8) * K0 + k + lc, &As[row * 64]);
            gload_lds16(Bg + (size_t)(row + l8) * K0 + k + lc, &Bs[row * 64]);
        }
        __syncthreads();
        bf16x8 af[2][2], bfr[2][2];
#pragma unroll
        for (int ks = 0; ks < 2; ++ks) {
#pragma unroll
            for (int im = 0; im < 2; ++im)
                af[ks][im] = *(const bf16x8*)&As[(wm * 32 + im * 16 + lrow) * 64 + ks * 32 + quad * 8];
#pragma unroll
            for (int in = 0; in < 2; ++in)
                bfr[ks][in] = *(const bf16x8*)&Bs[(wn * 32 + in * 16 + lrow) * 64 + ks * 32 + quad * 8];
        }
#pragma unroll
        for (int ks = 0; ks < 2; ++ks)
#pragma unroll
            for (int im = 0; im < 2; ++im)
#pragma unroll
                for (int in = 0; in < 2; ++in)
                    acc[im][in] = __builtin_amdgcn_mfma_f32_16x16x32_bf16(af[ks][im], bfr[ks][in], acc[im][in], 0, 0, 0);
        __syncthreads();
    }
#pragma unroll
    for (int im = 0; im < 2; ++im) {
        int row0 = mt * 64 + wm * 32 + im * 16 + quad * 4;
#pragma unroll
        for (int in = 0; in < 2; ++in) {
            int col = nt * 64 + wn * 32 + in * 16 + lrow;
#pragma unroll
            for (int r = 0; r < 4; ++r)
                atomicAdd(&C[(size_t)(row0 + r) * N00 + col], acc[im][in][r]);
        }
    }
}

// ---------------- fused GEMM (no split-K): bias + optional relu, bf16 or fp32 out ----------------
template <int BM, int BN, bool RELU, bool F32OUT>
__global__ __launch_bounds__(256) void gemm_fused(const bf16* __restrict__ A,
                                                  const bf16* __restrict__ Bt,
                                                  const float* __restrict__ bias,
                                                  bf16* __restrict__ Ob,
                                                  float* __restrict__ Of,
                                                  int K0, int N0, int Nreal, int kiters) {
    __shared__ __align__(16) bf16 As[BM * 64];
    __shared__ __align__(16) bf16 Bs[BN * 64];
    constexpr int WM = BM / 2, WN = BN / 2, RM = WM / 16, RN = WN / 16;
    const int mt = blockIdx.x, nt = blockIdx.y;
    const int tid = threadIdx.x, wave = tid >> 6, lane = tid & 63;
    const int wm = wave & 1, wn = wave >> 1;
    const int lrow = lane & 15, quad = lane >> 4;
    const int l8 = lane >> 3, lc = (lane & 7) * 8;

    const bf16* Ag = A  + (size_t)(mt * BM) * K0;
    const bf16* Bg = Bt + (size_t)(nt * BN) * K0;

    f32x4 acc[RM][RN] = {};
    for (int kk = 0; kk < kiters; ++kk) {
        const int k = kk * 64;
#pragma unroll
        for (int j = 0; j < BM / 32; ++j) {
            int row = j * 32 + wave * 8;
            gload_lds16(Ag + (size_t)(row + l8) * K0 + k + lc, &As[row * 64]);
        }
#pragma unroll
        for (int j = 0; j < BN / 32; ++j) {
            int row = j * 32 + wave * 8;
            gload_lds16(Bg + (size_t)(row + l8) * K0 + k + lc, &Bs[row * 64]);
        }
        __syncthreads();
        bf16x8 af[2][RM], bfr[2][RN];
#pragma unroll
        for (int ks = 0; ks < 2; ++ks) {
#pragma unroll
            for (int im = 0; im < RM; ++im)
                af[ks][im] = *(const bf16x8*)&As[(wm * WM + im * 16 + lrow) * 64 + ks * 32 + quad * 8];
#pragma unroll
            for (int in = 0; in < RN; ++in)
                bfr[ks][in] = *(const bf16x8*)&Bs[(wn * WN + in * 16 + lrow) * 64 + ks * 32 + quad * 8];
        }
#pragma unroll
        for (int ks = 0; ks < 2; ++ks)
#pragma unroll
            for (int im = 0; im < RM; ++im)
#pragma unroll
                for (int in = 0; in < RN; ++in)
                    acc[im][in] = __builtin_amdgcn_mfma_f32_16x16x32_bf16(af[ks][im], bfr[ks][in], acc[im][in], 0, 0, 0);
        __syncthreads();
    }
#pragma unroll
    for (int im = 0; im < RM; ++im) {
        int row0 = mt * BM + wm * WM + im * 16 + quad * 4;
#pragma unroll
        for (int in = 0; in < RN; ++in) {
            int col = nt * BN + wn * WN + in * 16 + lrow;
            float bv = (col < Nreal) ? bias[col] : 0.f;
#pragma unroll
            for (int r = 0; r < 4; ++r) {
                float v = acc[im][in][r] + bv;
                if (RELU) v = fmaxf(v, 0.f);
                if (F32OUT) Of[(size_t)(row0 + r) * N0 + col] = v;
                else        Ob[(size_t)(row0 + r) * N0 + col] = (bf16)v;
            }
        }
    }
}

// ---------------- relu + cvt to bf16, vectorized ----------------
__global__ __launch_bounds__(256) void relu_cvt4(const float* __restrict__ H,
                                                 bf16* __restrict__ Hb) {
    size_t t = (size_t)(blockIdx.x * 256 + threadIdx.x) * 4;
    float4 v = *(const float4*)&H[t];
    bf16 o[4] = {(bf16)fmaxf(v.x, 0.f), (bf16)fmaxf(v.y, 0.f),
                 (bf16)fmaxf(v.z, 0.f), (bf16)fmaxf(v.w, 0.f)};
    *(ushort4*)&Hb[t] = *(ushort4*)o;
}

// ---------------- cosine similarity over pairs ----------------
__global__ __launch_bounds__(64) void cosine_k(const float* __restrict__ E,
                                               float* __restrict__ out) {
    int b = blockIdx.x;
    int lane = threadIdx.x;
    const float* e1 = E + (size_t)(2 * b) * N03;
    const float* e2 = e1 + N03;
    float dot = 0.f, s1 = 0.f, s2 = 0.f;
#pragma unroll
    for (int i = lane; i < N03; i += 64) {    // pad cols are exactly 0
        float a = e1[i], c = e2[i];
        dot += a * c; s1 += a * a; s2 += c * c;
    }
#pragma unroll
    for (int off = 32; off; off >>= 1) {
        dot += __shfl_down(dot, off);
        s1  += __shfl_down(s1, off);
        s2  += __shfl_down(s2, off);
    }
    if (lane == 0) {
        float n1 = fmaxf(sqrtf(s1), 1e-6f);
        float n2 = fmaxf(sqrtf(s2), 1e-6f);
        out[b] = dot / (n1 * n2);
    }
}

extern "C" void kernel_launch(void* const* d_in, const int* in_sizes, int n_in,
                              void* d_out, int out_size, void* d_ws, size_t ws_size,
                              hipStream_t stream) {
    const float* mz    = (const float*)d_in[0];
    const float* inten = (const float*)d_in[1];
    const float* bw    = (const float*)d_in[2];
    const float* bb    = (const float*)d_in[3];
    const float* w0    = (const float*)d_in[4];
    const float* b0    = (const float*)d_in[5];
    const float* w1    = (const float*)d_in[6];
    const float* b1    = (const float*)d_in[7];
    const float* w2    = (const float*)d_in[8];
    const float* b2    = (const float*)d_in[9];
    const float* we    = (const float*)d_in[10];
    const float* be    = (const float*)d_in[11];
    float* out = (float*)d_out;

    char* ws = (char*)d_ws;
    size_t off = 0;
    auto alloc = [&](size_t bytes) { char* p = ws + off; off += (bytes + 255) & ~(size_t)255; return p; };
    float* xs  = (float*)alloc((size_t)NSPEC * K0A * 4);
    bf16*  A   = (bf16*) alloc((size_t)NSPEC * K0A * 2);
    bf16*  B0t = (bf16*) alloc((size_t)N00 * K0A * 2);
    bf16*  B1t = (bf16*) alloc((size_t)N01 * 1024 * 2);
    bf16*  B2t = (bf16*) alloc((size_t)N02 * 896 * 2);
    bf16*  BEt = (bf16*) alloc((size_t)N03 * 896 * 2);
    float* H0  = (float*)alloc((size_t)NSPEC * N00 * 4);
    bf16*  H0b = (bf16*) alloc((size_t)NSPEC * N00 * 2);
    bf16*  H1b = (bf16*) alloc((size_t)NSPEC * N01 * 2);
    bf16*  H2b = (bf16*) alloc((size_t)NSPEC * N02 * 2);
    float* E   = (float*)alloc((size_t)NSPEC * N03 * 4);

    // init xs (binner_b broadcast, zero pad) + H0 (b0 broadcast, zero pad)
    init_fused<<<5632, 256, 0, stream>>>(bb, b0, xs, H0);
    // sparse binning + binner matmul fused as scatter
    bin_scatter<<<1024, 256, 0, stream>>>(mz, inten, bw, xs);
    cvt_a<<<5120, 256, 0, stream>>>(xs, A);
    // weights -> bf16 N-major (k contiguous)
    transpose_cvt<<<dim3(32, 320), 256, 0, stream>>>(w0, B0t, BOUT, 1000, K0A, N00);
    transpose_cvt<<<dim3(28, 32),  256, 0, stream>>>(w1, B1t, 1000, 800, 1024, N01);
    transpose_cvt<<<dim3(28, 28),  256, 0, stream>>>(w2, B2t, 800,  800, 896,  N02);
    transpose_cvt<<<dim3(14, 28),  256, 0, stream>>>(we, BEt, 800,  400, 896,  N03);
    // MLP
    gemm0_splitk<<<1024, 256, 0, stream>>>(A, B0t, H0);
    relu_cvt4<<<512, 256, 0, stream>>>(H0, H0b);
    gemm_fused<32, 64, true,  false><<<dim3(16, 14), 256, 0, stream>>>(H0b, B1t, b1, H1b, nullptr, 1024, N01, 800, 16);
    gemm_fused<32, 64, true,  false><<<dim3(16, 14), 256, 0, stream>>>(H1b, B2t, b2, H2b, nullptr, 896,  N02, 800, 14);
    gemm_fused<32, 64, false, true ><<<dim3(16, 7),  256, 0, stream>>>(H2b, BEt, be, nullptr, E,    896,  N03, 400, 14);
    // cosine
    cosine_k<<<256, 64, 0, stream>>>(E, out);
}

// Round 3
// 220.737 us; speedup vs baseline: 1.3525x; 1.1226x over previous
//
#include <hip/hip_runtime.h>

typedef __bf16 bf16;
typedef __bf16 bf16x8 __attribute__((ext_vector_type(8)));
typedef float  f32x4  __attribute__((ext_vector_type(4)));

// Problem constants
#define NSPEC   512          // 256 pairs * 2
#define BOUT    9999         // GROUPS*3
#define K0A     10240        // BOUT padded to 8*20*64 (ksplit*kiters*BK)
#define N00     1024         // 1000 padded
#define N01     896          // 800 padded
#define N02     896
#define N03     448          // 400 padded (14*32)

// async global->LDS, 16B per lane; lds base must be wave-uniform (HW adds lane*16)
__device__ __forceinline__ void gload_lds16(const bf16* g, bf16* l) {
    auto* gp = reinterpret_cast<const __attribute__((address_space(1))) unsigned int*>(
        reinterpret_cast<uintptr_t>(g));
    auto* lp = reinterpret_cast<__attribute__((address_space(3))) unsigned int*>(
        reinterpret_cast<uintptr_t>(l));
    __builtin_amdgcn_global_load_lds(gp, lp, 16, 0, 0);
}

// ---------------- transpose tile helper: src (K x N) fp32 -> dst (N0 x K0) bf16 ----------------
__device__ __forceinline__ void transpose_tile(const float* __restrict__ src,
                                               bf16* __restrict__ dst,
                                               int K, int N, int K0, int bx, int by) {
    __shared__ float tile[32][33];
    int n0 = bx * 32, k0 = by * 32;
    int t = threadIdx.x;
    {
        int kr = t >> 3, nc = (t & 7) * 4;
        int gk = k0 + kr;
#pragma unroll
        for (int e = 0; e < 4; ++e) {
            int gn = n0 + nc + e;
            tile[kr][nc + e] = (gk < K && gn < N) ? src[(size_t)gk * N + gn] : 0.0f;
        }
    }
    __syncthreads();
    {
        int nr = t >> 3, kc = (t & 7) * 4;
        bf16 v[4];
#pragma unroll
        for (int e = 0; e < 4; ++e) v[e] = (bf16)tile[kc + e][nr];
        *(ushort4*)&dst[(size_t)(n0 + nr) * K0 + k0 + kc] = *(ushort4*)v;
    }
}

// ---------------- mega-prep: bias-broadcast inits + all weight transposes ----------------
__global__ __launch_bounds__(256) void prep(const float* __restrict__ bb,
                                            const float* __restrict__ b0,
                                            const float* __restrict__ w0,
                                            const float* __restrict__ w1,
                                            const float* __restrict__ w2,
                                            const float* __restrict__ we,
                                            float* __restrict__ xs,
                                            float* __restrict__ H0,
                                            bf16* __restrict__ B0t,
                                            bf16* __restrict__ B1t,
                                            bf16* __restrict__ B2t,
                                            bf16* __restrict__ BEt) {
    int b = blockIdx.x;
    if (b < 5120) {                       // xs <- broadcast binner_b (512 x 10240)
        int t = b * 256 + threadIdx.x;
        int row = t / 2560, c = (t % 2560) * 4;
        float4 v;
        v.x = (c + 0 < BOUT) ? bb[c + 0] : 0.f;
        v.y = (c + 1 < BOUT) ? bb[c + 1] : 0.f;
        v.z = (c + 2 < BOUT) ? bb[c + 2] : 0.f;
        v.w = (c + 3 < BOUT) ? bb[c + 3] : 0.f;
        *(float4*)&xs[(size_t)row * K0A + c] = v;
    } else if (b < 5632) {                // H0 <- broadcast b0 (512 x 1024)
        int u = (b - 5120) * 256 + threadIdx.x;
        int row = u >> 8, c = (u & 255) * 4;
        float4 v;
        v.x = (c + 0 < 1000) ? b0[c + 0] : 0.f;
        v.y = (c + 1 < 1000) ? b0[c + 1] : 0.f;
        v.z = (c + 2 < 1000) ? b0[c + 2] : 0.f;
        v.w = (c + 3 < 1000) ? b0[c + 3] : 0.f;
        *(float4*)&H0[(size_t)row * N00 + c] = v;
    } else if (b < 15872) {               // w0 -> B0t (1024 x 10240), 32 x 320 tiles
        int r = b - 5632;
        transpose_tile(w0, B0t, BOUT, 1000, K0A, r & 31, r >> 5);
    } else if (b < 16768) {               // w1 -> B1t (896 x 1024), 28 x 32 tiles
        int r = b - 15872;
        transpose_tile(w1, B1t, 1000, 800, 1024, r % 28, r / 28);
    } else if (b < 17552) {               // w2 -> B2t (896 x 896), 28 x 28 tiles
        int r = b - 16768;
        transpose_tile(w2, B2t, 800, 800, 896, r % 28, r / 28);
    } else {                              // we -> BEt (448 x 896), 14 x 28 tiles
        int r = b - 17552;
        transpose_tile(we, BEt, 800, 400, 896, r % 14, r / 14);
    }
}

// ---------------- peak scatter (fused binning + grouped binner matmul) ----------------
__global__ __launch_bounds__(256) void bin_scatter(const float* __restrict__ mz,
                                                   const float* __restrict__ inten,
                                                   const float* __restrict__ bw,
                                                   float* __restrict__ xs) {
    int t = blockIdx.x * 256 + threadIdx.x;   // 0..262143
    float m = mz[t];
    float v = inten[t];
    bool mask = (m >= 0.0f) && (m < 1000.0f);
    int idx = (int)(m / 0.01f);               // IEEE div + trunc, matches astype(int32)
    idx = min(max(idx, 0), 99999);
    if (mask && idx < 99990) {
        int g = idx / 30;
        float val = sqrtf(v);                 // inten ** 0.5
        const float* w = bw + (size_t)idx * 3;
        float* x = xs + (size_t)(t >> 9) * K0A + g * 3;
        atomicAdd(x + 0, val * w[0]);
        atomicAdd(x + 1, val * w[1]);
        atomicAdd(x + 2, val * w[2]);
    }
}

// ---------------- fp32 -> bf16 flat vector copy (xs is padded, contiguous) ----------------
__global__ __launch_bounds__(256) void cvt_a(const float* __restrict__ xs,
                                             bf16* __restrict__ A) {
    size_t t = (size_t)(blockIdx.x * 256 + threadIdx.x) * 4;
    float4 v = *(const float4*)&xs[t];
    bf16 o[4] = {(bf16)v.x, (bf16)v.y, (bf16)v.z, (bf16)v.w};
    *(ushort4*)&A[t] = *(ushort4*)o;
}

// ---------------- GEMM0: 64x64xBK64 tiles, split-K=8 XCD-pinned, dbuf pipelined ----------------
__global__ __launch_bounds__(256) void gemm0_splitk(const bf16* __restrict__ A,
                                                    const bf16* __restrict__ Bt,
                                                    float* __restrict__ C) {
    constexpr int K0 = K0A, KITERS = 20;
    __shared__ __align__(16) bf16 As[2][64 * 64];
    __shared__ __align__(16) bf16 Bs[2][64 * 64];
    const int bid = blockIdx.x;
    const int kp = bid & 7;                   // kp == XCD (round-robin dispatch)
    const int tile = bid >> 3;
    const int mt = tile & 7, nt = tile >> 3;
    const int tid = threadIdx.x, wave = tid >> 6, lane = tid & 63;
    const int wm = wave & 1, wn = wave >> 1;
    const int lrow = lane & 15, quad = lane >> 4;
    const int l8 = lane >> 3, lc = (lane & 7) * 8;

    const bf16* Ag = A  + (size_t)(mt * 64) * K0 + kp * KITERS * 64;
    const bf16* Bg = Bt + (size_t)(nt * 64) * K0 + kp * KITERS * 64;

    auto stage = [&](int buf, int kk) {
        const int k = kk * 64;
#pragma unroll
        for (int j = 0; j < 2; ++j) {
            int row = j * 32 + wave * 8;
            gload_lds16(Ag + (size_t)(row + l8) * K0 + k + lc, &As[buf][row * 64]);
            gload_lds16(Bg + (size_t)(row + l8) * K0 + k + lc, &Bs[buf][row * 64]);
        }
    };

    f32x4 acc[2][2] = {};
    stage(0, 0);
    for (int kk = 0; kk < KITERS; ++kk) {
        const int cur = kk & 1;
        __syncthreads();                      // buf[cur] loads drained (vmcnt0 at barrier)
        if (kk + 1 < KITERS) stage(cur ^ 1, kk + 1);  // prefetch overlaps compute below
        bf16x8 af[2][2], bfr[2][2];
#pragma unroll
        for (int ks = 0; ks < 2; ++ks) {
#pragma unroll
            for (int im = 0; im < 2; ++im)
                af[ks][im] = *(const bf16x8*)&As[cur][(wm * 32 + im * 16 + lrow) * 64 + ks * 32 + quad * 8];
#pragma unroll
            for (int in = 0; in < 2; ++in)
                bfr[ks][in] = *(const bf16x8*)&Bs[cur][(wn * 32 + in * 16 + lrow) * 64 + ks * 32 + quad * 8];
        }
#pragma unroll
        for (int ks = 0; ks < 2; ++ks)
#pragma unroll
            for (int im = 0; im < 2; ++im)
#pragma unroll
                for (int in = 0; in < 2; ++in)
                    acc[im][in] = __builtin_amdgcn_mfma_f32_16x16x32_bf16(af[ks][im], bfr[ks][in], acc[im][in], 0, 0, 0);
    }
#pragma unroll
    for (int im = 0; im < 2; ++im) {
        int row0 = mt * 64 + wm * 32 + im * 16 + quad * 4;
#pragma unroll
        for (int in = 0; in < 2; ++in) {
            int col = nt * 64 + wn * 32 + in * 16 + lrow;
#pragma unroll
            for (int r = 0; r < 4; ++r)
                atomicAdd(&C[(size_t)(row0 + r) * N00 + col], acc[im][in][r]);
        }
    }
}

// ---------------- small GEMM: 32x32 tiles, BK=128, dbuf, fused bias(+relu) epilogue ----------------
template <bool RELU, bool F32OUT>
__global__ __launch_bounds__(256) void gemm_small(const bf16* __restrict__ A,
                                                  const bf16* __restrict__ Bt,
                                                  const float* __restrict__ bias,
                                                  bf16* __restrict__ Ob,
                                                  float* __restrict__ Of,
                                                  int K0, int N0, int Nreal,
                                                  int kiters, int ntiles) {
    __shared__ __align__(16) bf16 As[2][32 * 128];
    __shared__ __align__(16) bf16 Bs[2][32 * 128];
    const int bid = blockIdx.x;
    const int mt = bid / ntiles, nt = bid % ntiles;
    const int tid = threadIdx.x, wave = tid >> 6, lane = tid & 63;
    const int wm = wave & 1, wn = wave >> 1;
    const int lrow = lane & 15, quad = lane >> 4;
    const int l4 = lane >> 4, lc = (lane & 15) * 8;   // 4 rows per gload call

    const bf16* Ag = A  + (size_t)(mt * 32) * K0;
    const bf16* Bg = Bt + (size_t)(nt * 32) * K0;

    auto stage = [&](int buf, int kk) {
        const int k = kk * 128;
#pragma unroll
        for (int j = wave; j < 8; j += 4) {           // j in {wave, wave+4}
            int row = j * 4;
            gload_lds16(Ag + (size_t)(row + l4) * K0 + k + lc, &As[buf][row * 128]);
            gload_lds16(Bg + (size_t)(row + l4) * K0 + k + lc, &Bs[buf][row * 128]);
        }
    };

    f32x4 acc = {};
    stage(0, 0);
    for (int kk = 0; kk < kiters; ++kk) {
        const int cur = kk & 1;
        __syncthreads();
        if (kk + 1 < kiters) stage(cur ^ 1, kk + 1);
#pragma unroll
        for (int ks = 0; ks < 4; ++ks) {
            bf16x8 af  = *(const bf16x8*)&As[cur][(wm * 16 + lrow) * 128 + ks * 32 + quad * 8];
            bf16x8 bfr = *(const bf16x8*)&Bs[cur][(wn * 16 + lrow) * 128 + ks * 32 + quad * 8];
            acc = __builtin_amdgcn_mfma_f32_16x16x32_bf16(af, bfr, acc, 0, 0, 0);
        }
    }
    int row0 = mt * 32 + wm * 16 + quad * 4;
    int col  = nt * 32 + wn * 16 + lrow;
    float bv = (col < Nreal) ? bias[col] : 0.f;
#pragma unroll
    for (int r = 0; r < 4; ++r) {
        float v = acc[r] + bv;
        if (RELU) v = fmaxf(v, 0.f);
        if (F32OUT) Of[(size_t)(row0 + r) * N0 + col] = v;
        else        Ob[(size_t)(row0 + r) * N0 + col] = (bf16)v;
    }
}

// ---------------- relu + cvt to bf16, vectorized ----------------
__global__ __launch_bounds__(256) void relu_cvt4(const float* __restrict__ H,
                                                 bf16* __restrict__ Hb) {
    size_t t = (size_t)(blockIdx.x * 256 + threadIdx.x) * 4;
    float4 v = *(const float4*)&H[t];
    bf16 o[4] = {(bf16)fmaxf(v.x, 0.f), (bf16)fmaxf(v.y, 0.f),
                 (bf16)fmaxf(v.z, 0.f), (bf16)fmaxf(v.w, 0.f)};
    *(ushort4*)&Hb[t] = *(ushort4*)o;
}

// ---------------- cosine similarity over pairs ----------------
__global__ __launch_bounds__(64) void cosine_k(const float* __restrict__ E,
                                               float* __restrict__ out) {
    int b = blockIdx.x;
    int lane = threadIdx.x;
    const float* e1 = E + (size_t)(2 * b) * N03;
    const float* e2 = e1 + N03;
    float dot = 0.f, s1 = 0.f, s2 = 0.f;
#pragma unroll
    for (int i = lane; i < N03; i += 64) {    // pad cols are exactly 0
        float a = e1[i], c = e2[i];
        dot += a * c; s1 += a * a; s2 += c * c;
    }
#pragma unroll
    for (int off = 32; off; off >>= 1) {
        dot += __shfl_down(dot, off);
        s1  += __shfl_down(s1, off);
        s2  += __shfl_down(s2, off);
    }
    if (lane == 0) {
        float n1 = fmaxf(sqrtf(s1), 1e-6f);
        float n2 = fmaxf(sqrtf(s2), 1e-6f);
        out[b] = dot / (n1 * n2);
    }
}

extern "C" void kernel_launch(void* const* d_in, const int* in_sizes, int n_in,
                              void* d_out, int out_size, void* d_ws, size_t ws_size,
                              hipStream_t stream) {
    const float* mz    = (const float*)d_in[0];
    const float* inten = (const float*)d_in[1];
    const float* bw    = (const float*)d_in[2];
    const float* bb    = (const float*)d_in[3];
    const float* w0    = (const float*)d_in[4];
    const float* b0    = (const float*)d_in[5];
    const float* w1    = (const float*)d_in[6];
    const float* b1    = (const float*)d_in[7];
    const float* w2    = (const float*)d_in[8];
    const float* b2    = (const float*)d_in[9];
    const float* we    = (const float*)d_in[10];
    const float* be    = (const float*)d_in[11];
    float* out = (float*)d_out;

    char* ws = (char*)d_ws;
    size_t off = 0;
    auto alloc = [&](size_t bytes) { char* p = ws + off; off += (bytes + 255) & ~(size_t)255; return p; };
    float* xs  = (float*)alloc((size_t)NSPEC * K0A * 4);
    bf16*  A   = (bf16*) alloc((size_t)NSPEC * K0A * 2);
    bf16*  B0t = (bf16*) alloc((size_t)N00 * K0A * 2);
    bf16*  B1t = (bf16*) alloc((size_t)N01 * 1024 * 2);
    bf16*  B2t = (bf16*) alloc((size_t)N02 * 896 * 2);
    bf16*  BEt = (bf16*) alloc((size_t)N03 * 896 * 2);
    float* H0  = (float*)alloc((size_t)NSPEC * N00 * 4);
    bf16*  H0b = (bf16*) alloc((size_t)NSPEC * N00 * 2);
    bf16*  H1b = (bf16*) alloc((size_t)NSPEC * N01 * 2);
    bf16*  H2b = (bf16*) alloc((size_t)NSPEC * N02 * 2);
    float* E   = (float*)alloc((size_t)NSPEC * N03 * 4);

    // 1: all init + all weight transposes
    prep<<<17944, 256, 0, stream>>>(bb, b0, w0, w1, w2, we, xs, H0, B0t, B1t, B2t, BEt);
    // 2: sparse binning + binner matmul fused as scatter
    bin_scatter<<<1024, 256, 0, stream>>>(mz, inten, bw, xs);
    // 3: xs -> bf16 A
    cvt_a<<<5120, 256, 0, stream>>>(xs, A);
    // 4: big GEMM, split-K=8 XCD-pinned
    gemm0_splitk<<<1024, 256, 0, stream>>>(A, B0t, H0);
    // 5: relu + cvt
    relu_cvt4<<<512, 256, 0, stream>>>(H0, H0b);
    // 6-8: small fused GEMMs
    gemm_small<true,  false><<<448, 256, 0, stream>>>(H0b, B1t, b1, H1b, nullptr, 1024, N01, 800, 8, 28);
    gemm_small<true,  false><<<448, 256, 0, stream>>>(H1b, B2t, b2, H2b, nullptr, 896,  N02, 800, 7, 28);
    gemm_small<false, true ><<<224, 256, 0, stream>>>(H2b, BEt, be, nullptr, E,    896,  N03, 400, 7, 14);
    // 9: cosine
    cosine_k<<<256, 64, 0, stream>>>(E, out);
}